// Round 3
// baseline (430.758 us; speedup 1.0000x reference)
//
#include <hip/hip_runtime.h>
#include <hip/hip_bf16.h>

#define NTOK 16384
#define HD   4096
#define NE   64
#define KSPLIT 4
#define KS    (HD / KSPLIT)   // 1024 K per wave
#define NSTEP (KS / 32)       // 32 K-steps per wave
#define SL2   68              // logits LDS row stride (floats)
#define W2OFF 256             // float offset of W2 inside ws
#define W2JSTR 131072         // 16 experts * 512 chunks * 16 elems

typedef __bf16 bf16x8 __attribute__((ext_vector_type(8)));
typedef float  f32x4  __attribute__((ext_vector_type(4)));

__device__ __forceinline__ f32x4 mfma16(bf16x8 a, bf16x8 b, f32x4 c) {
    return __builtin_amdgcn_mfma_f32_16x16x32_bf16(a, b, c, 0, 0, 0);
}

// Pre-convert W_gate fp32 -> bf16 hi/lo, packed per 8-k chunk: [hi0..7][lo0..7].
// Also zeroes the 129 reduction scalars at ws[0..129).
__global__ void prep_kernel(const float* __restrict__ Wg, float* __restrict__ ws) {
    const int idx = blockIdx.x * 256 + threadIdx.x;   // chunk id 0..32767 (e*512+ch)
    if (blockIdx.x == 0 && threadIdx.x < 129) ws[threadIdx.x] = 0.0f;
    __bf16* W2 = (__bf16*)(ws + W2OFF);
    const float4* src = (const float4*)(Wg + (size_t)idx * 8);
    float4 q0 = src[0], q1 = src[1];
    float xs[8] = {q0.x, q0.y, q0.z, q0.w, q1.x, q1.y, q1.z, q1.w};
    bf16x8 hi, lo;
    #pragma unroll
    for (int e = 0; e < 8; ++e) {
        __bf16 h = (__bf16)xs[e];
        hi[e] = h;
        lo[e] = (__bf16)(xs[e] - (float)h);
    }
    *(bf16x8*)(W2 + (size_t)idx * 16)     = hi;
    *(bf16x8*)(W2 + (size_t)idx * 16 + 8) = lo;
}

__global__ __launch_bounds__(256, 4) void router_kernel(
    const float* __restrict__ hs,
    float* __restrict__ out,
    float* __restrict__ ws)
{
    __shared__ float sRed[4 * 16 * SL2];   // per-wave partial logits, 17408 B
    __shared__ float sInv[16];
    __shared__ float sPp[256];
    __shared__ float sCnt[64];
    __shared__ float sZ;

    const int tid  = threadIdx.x;
    const int t0   = blockIdx.x * 16;     // 16 tokens per block
    const int wv   = tid >> 6;            // wave 0..3 -> K range wv*1024
    const int lane = tid & 63;
    const int fm   = lane & 15;
    const int fq   = lane >> 4;

    if (tid < 64) sCnt[tid] = 0.0f;
    if (tid == 0) sZ = 0.0f;

    const __bf16* W2 = (const __bf16*)(ws + W2OFF);
    const int k0 = wv * KS;
    // A: lane = token row (fm), k = k0 + fq*8 + it*32
    const float* aPtr = hs + (size_t)(t0 + fm) * HD + k0 + fq * 8;
    // B: elem offset for expert block j: j*W2JSTR + (fm*512 + ch)*16, ch = k0/8 + it*4 + fq
    const int bOff = (fm * 512 + (k0 >> 3) + fq) * 16;

    f32x4 acc[4];
    #pragma unroll
    for (int j = 0; j < 4; ++j) acc[j] = (f32x4){0.f, 0.f, 0.f, 0.f};

    float4 a_raw[2][2];
    bf16x8 b_frag[2][4][2];

    // prologue: load K-step 0 into buffer 0
    a_raw[0][0] = *(const float4*)(aPtr);
    a_raw[0][1] = *(const float4*)(aPtr + 4);
    #pragma unroll
    for (int j = 0; j < 4; ++j) {
        const __bf16* bp = W2 + j * W2JSTR + bOff;
        b_frag[0][j][0] = *(const bf16x8*)(bp);
        b_frag[0][j][1] = *(const bf16x8*)(bp + 8);
    }

    #pragma unroll 2
    for (int it = 0; it < NSTEP; ++it) {
        const int cur = it & 1, nxt = cur ^ 1;
        if (it + 1 < NSTEP) {
            const float* ap = aPtr + (it + 1) * 32;
            a_raw[nxt][0] = *(const float4*)(ap);
            a_raw[nxt][1] = *(const float4*)(ap + 4);
            const __bf16* bp = W2 + bOff + (it + 1) * 64;
            #pragma unroll
            for (int j = 0; j < 4; ++j) {
                b_frag[nxt][j][0] = *(const bf16x8*)(bp + j * W2JSTR);
                b_frag[nxt][j][1] = *(const bf16x8*)(bp + j * W2JSTR + 8);
            }
        }
        // convert A fp32 -> bf16 hi/lo in registers
        float4 q0 = a_raw[cur][0], q1 = a_raw[cur][1];
        float xs[8] = {q0.x, q0.y, q0.z, q0.w, q1.x, q1.y, q1.z, q1.w};
        bf16x8 ahi, alo;
        #pragma unroll
        for (int e = 0; e < 8; ++e) {
            __bf16 h = (__bf16)xs[e];
            ahi[e] = h;
            alo[e] = (__bf16)(xs[e] - (float)h);
        }
        #pragma unroll
        for (int j = 0; j < 4; ++j) {
            acc[j] = mfma16(ahi, b_frag[cur][j][0], acc[j]);
            acc[j] = mfma16(alo, b_frag[cur][j][0], acc[j]);
            acc[j] = mfma16(ahi, b_frag[cur][j][1], acc[j]);
            acc[j] = mfma16(alo, b_frag[cur][j][1], acc[j]);
        }
    }

    // ---- combine K-split partials: C/D layout col(fm)=expert-within-16, row=fq*4+r=token
    {
        float* my = &sRed[wv * 16 * SL2];
        #pragma unroll
        for (int j = 0; j < 4; ++j)
            #pragma unroll
            for (int r = 0; r < 4; ++r)
                my[(fq * 4 + r) * SL2 + (j * 16 + fm)] = acc[j][r];
    }
    __syncthreads();
    for (int s = tid; s < 1024; s += 256) {
        const int t = s >> 6, e = s & 63;
        const int o = t * SL2 + e;
        sRed[o] = sRed[o] + sRed[16 * SL2 + o] + sRed[32 * SL2 + o] + sRed[48 * SL2 + o];
    }
    __syncthreads();

    // ---- softmax/top-2: 16 lanes per token, 4 experts per lane
    const int g = tid >> 4;     // token 0..15
    const int l = tid & 15;
    float* Lrow = &sRed[g * SL2 + l * 4];
    float lv[4];
    float m = -3.0e38f;
    #pragma unroll
    for (int c = 0; c < 4; ++c) { lv[c] = Lrow[c]; m = fmaxf(m, lv[c]); }
    m = fmaxf(m, __shfl_xor(m, 1, 64));
    m = fmaxf(m, __shfl_xor(m, 2, 64));
    m = fmaxf(m, __shfl_xor(m, 4, 64));
    m = fmaxf(m, __shfl_xor(m, 8, 64));

    float v1 = -3.0e38f, v2 = -3.0e38f; int i1 = 0, i2 = 0;
    float ssum = 0.0f;
    #pragma unroll
    for (int c = 0; c < 4; ++c) {
        const float val = lv[c]; const int idx = l * 4 + c;
        const float ev = __expf(val - m);
        Lrow[c] = ev;            // overwrite logits with exp(l - m)
        ssum += ev;
        if (val > v1) { v2 = v1; i2 = i1; v1 = val; i1 = idx; }
        else if (val > v2) { v2 = val; i2 = idx; }
    }
    ssum += __shfl_xor(ssum, 1, 64);
    ssum += __shfl_xor(ssum, 2, 64);
    ssum += __shfl_xor(ssum, 4, 64);
    ssum += __shfl_xor(ssum, 8, 64);

    #pragma unroll
    for (int s = 1; s <= 8; s <<= 1) {
        const float ov1 = __shfl_xor(v1, s, 64);
        const int   oi1 = __shfl_xor(i1, s, 64);
        const float ov2 = __shfl_xor(v2, s, 64);
        const int   oi2 = __shfl_xor(i2, s, 64);
        float n1, n2; int ni1, ni2;
        const bool ofirst = (ov1 > v1) || (ov1 == v1 && oi1 < i1);
        if (ofirst) {
            n1 = ov1; ni1 = oi1;
            const bool osec = (ov2 > v1) || (ov2 == v1 && oi2 < i1);
            n2 = osec ? ov2 : v1; ni2 = osec ? oi2 : i1;
        } else {
            n1 = v1; ni1 = i1;
            const bool asec = (v2 > ov1) || (v2 == ov1 && i2 < oi1);
            n2 = asec ? v2 : ov1; ni2 = asec ? i2 : oi1;
        }
        v1 = n1; i1 = ni1; v2 = n2; i2 = ni2;
    }

    if (l == 0) {
        const float e1 = __expf(v1 - m), e2 = __expf(v2 - m);
        const float winv = 1.0f / (e1 + e2);
        const int token = t0 + g;
        out[2 * token]     = e1 * winv;
        out[2 * token + 1] = e2 * winv;
        out[2 * NTOK + 2 * token]     = (float)i1;   // indices stored as f32
        out[2 * NTOK + 2 * token + 1] = (float)i2;
        const float lse = m + __logf(ssum);
        atomicAdd(&sZ, lse * lse);
        atomicAdd(&sCnt[i1], 1.0f);
        atomicAdd(&sCnt[i2], 1.0f);
        sInv[g] = 1.0f / ssum;
    }
    __syncthreads();

    // ---- per-expert prob sums over the 16 tokens, then global atomics
    {
        const int e = tid & 63;
        const int q = tid >> 6;
        float part = 0.0f;
        #pragma unroll
        for (int t = 0; t < 4; ++t) {
            const int tok = q * 4 + t;
            part += sRed[tok * SL2 + e] * sInv[tok];
        }
        sPp[q * 64 + e] = part;
    }
    __syncthreads();
    if (tid < 64) {
        const float ps = sPp[tid] + sPp[64 + tid] + sPp[128 + tid] + sPp[192 + tid];
        atomicAdd(&ws[tid], ps);             // sum of probs per expert
        atomicAdd(&ws[64 + tid], sCnt[tid]); // top-2 counts per expert
    }
    if (tid == 0) atomicAdd(&ws[128], sZ);
}

__global__ void finalize_kernel(const float* __restrict__ ws, float* __restrict__ out) {
    const int e = threadIdx.x;   // 64 threads, one wave
    const float P = ws[e] * (1.0f / NTOK);
    const float f = ws[64 + e] * (1.0f / (NTOK * 2));
    float term = f * P;
    #pragma unroll
    for (int s = 32; s >= 1; s >>= 1) term += __shfl_xor(term, s, 64);
    if (e == 0) {
        const float lb = 64.0f * term;
        const float z  = ws[128] * (1.0f / NTOK);
        out[4 * NTOK] = 0.001f * lb + 0.001f * z;
    }
}

extern "C" void kernel_launch(void* const* d_in, const int* in_sizes, int n_in,
                              void* d_out, int out_size, void* d_ws, size_t ws_size,
                              hipStream_t stream) {
    const float* hs = (const float*)d_in[0];
    const float* Wg = (const float*)d_in[1];
    float* out = (float*)d_out;
    float* ws  = (float*)d_ws;

    hipLaunchKernelGGL(prep_kernel, dim3(128), dim3(256), 0, stream, Wg, ws);
    hipLaunchKernelGGL(router_kernel, dim3(NTOK / 16), dim3(256), 0, stream, hs, out, ws);
    hipLaunchKernelGGL(finalize_kernel, dim3(1), dim3(64), 0, stream, ws, out);
}